// Round 11
// baseline (288.148 us; speedup 1.0000x reference)
//
#include <hip/hip_runtime.h>
#include <hip/hip_bf16.h>
#include <stdint.h>

// Problem constants (fixed by reference)
#define TSEQ   2048
#define DMODEL 1024
#define NH     16
#define HDIM   64
#define NKVH   4

typedef __attribute__((ext_vector_type(8))) short short8;
typedef __attribute__((ext_vector_type(8))) _Float16 half8;
typedef __attribute__((ext_vector_type(4))) float f32x4;
typedef __hip_bfloat16 bf16;

// async global->LDS, 16B per lane (linear LDS dest = wave base + lane*16)
__device__ __forceinline__ void gload16(const void* g, void* l) {
    __builtin_amdgcn_global_load_lds(
        (const __attribute__((address_space(1))) uint32_t*)g,
        (__attribute__((address_space(3))) uint32_t*)l, 16, 0, 0);
}

// priority comparator: higher score wins; tie -> lower index wins (matches jax top_k)
__device__ __forceinline__ bool pgt(float as, int ai, float bs, int bi) {
    return (as > bs) || (as == bs && ai < bi);
}

// full bitonic sort across 64 lanes, ascending by priority (validated R6)
__device__ __forceinline__ void bsort(float& s, int& i, int lane) {
#pragma unroll
    for (int k = 2; k <= 64; k <<= 1) {
#pragma unroll
        for (int j = k >> 1; j > 0; j >>= 1) {
            float os = __shfl_xor(s, j, 64);
            int   oi = __shfl_xor(i, j, 64);
            bool lower = (lane & j) == 0;
            bool asc   = (lane & k) == 0;
            bool wmin  = (lower == asc);
            bool takeo = (pgt(s, i, os, oi) == wmin);
            if (takeo) { s = os; i = oi; }
        }
    }
}

// bitonic -> ascending cleanup (6 stages) (validated R6)
__device__ __forceinline__ void bmerge(float& s, int& i, int lane) {
#pragma unroll
    for (int j = 32; j > 0; j >>= 1) {
        float os = __shfl_xor(s, j, 64);
        int   oi = __shfl_xor(i, j, 64);
        bool lower = (lane & j) == 0;
        bool takeo = (pgt(s, i, os, oi) == lower);
        if (takeo) { s = os; i = oi; }
    }
}

// ---- fp32 -> bf16 conversion of x ----
__global__ __launch_bounds__(256) void convert_x(
    const float* __restrict__ x, bf16* __restrict__ cx)
{
    const size_t i0 = (size_t)blockIdx.x * 256 + threadIdx.x;
    const size_t stride = (size_t)gridDim.x * 256;
    for (size_t i = i0; i < 2097152; i += stride) cx[i] = __float2bfloat16(x[i]);
}

// ---- fp32 [R][C] -> bf16 [C][R] tiled transpose-convert (weights, one-shot) ----
__global__ __launch_bounds__(256) void transpose_conv(
    const float* __restrict__ in, bf16* __restrict__ out, int R, int Cc)
{
    __shared__ float tile[32][33];
    const int bx = blockIdx.x * 32;   // col base (n)
    const int by = blockIdx.y * 32;   // row base (k)
    const int tx = threadIdx.x & 31, ty = threadIdx.x >> 5;   // 32 x 8
#pragma unroll
    for (int i = 0; i < 32; i += 8)
        tile[ty + i][tx] = in[(size_t)(by + ty + i) * Cc + bx + tx];
    __syncthreads();
#pragma unroll
    for (int i = 0; i < 32; i += 8)
        out[(size_t)(bx + ty + i) * R + by + tx] = __float2bfloat16(tile[tx][ty + i]);
}

// ---- MFMA GEMM: A[M,K](bf16) @ BT[N,K](bf16)^T + bias, fused epilogue ----
// MODE 0: C[row,col] = acc+bias (fp32)                      (out projection)
// MODE 1: per-row RMSnorm (64-col head tile) * wn * 0.125 -> f16 fh[row,col]  (Q)
// MODE 2: n0<256: k-head RMSnorm * wn -> f16 fh[(kvh,row),d];
//         n0>=256: v -> fp32 vout[(kvh,row),d]               (KV)
// (validated R10)
template<int MODE>
__global__ __launch_bounds__(256) void gemm_bias(
    const bf16* __restrict__ A, const bf16* __restrict__ BT,
    const float* __restrict__ bias, float* __restrict__ C,
    _Float16* __restrict__ fh, float* __restrict__ vout,
    const float* __restrict__ wn, int M, int N, int K)
{
    __shared__ short As[64][64];   // (m, k-slot-swizzled)  8KB
    __shared__ short Bs[64][64];   // (n, k-slot-swizzled)  8KB
    const int tid = threadIdx.x;
    const int m0 = blockIdx.y * 64, n0 = blockIdx.x * 64;
    const int w = tid >> 6, lane = tid & 63;
    const int q4 = lane >> 4, mm = lane & 15;
    f32x4 acc[4];
#pragma unroll
    for (int nb = 0; nb < 4; ++nb) acc[nb] = (f32x4){0.f, 0.f, 0.f, 0.f};

    const int ar = tid >> 3;                       // 0..31
    const int sslot = (tid & 7) ^ (ar & 7);        // swizzled global k-slot
    const short* Ag = (const short*)A + (size_t)(m0 + ar) * K + sslot * 8;
    const short* Ag2 = (const short*)A + (size_t)(m0 + ar + 32) * K + ((tid & 7) ^ ((ar + 32) & 7)) * 8;
    const short* Bg = (const short*)BT + (size_t)(n0 + ar) * K + sslot * 8;
    const short* Bg2 = (const short*)BT + (size_t)(n0 + ar + 32) * K + ((tid & 7) ^ ((ar + 32) & 7)) * 8;

    const int xm = mm & 7;
    const short* Asf = (const short*)As;
    const short* Bsf = (const short*)Bs;
    const int aoff0 = (w * 16 + mm) * 64 + ((q4 ^ xm)) * 8;
    const int aoff1 = (w * 16 + mm) * 64 + (((4 + q4) ^ xm)) * 8;
    int boff0[4], boff1[4];
#pragma unroll
    for (int nb = 0; nb < 4; ++nb) {
        boff0[nb] = (nb * 16 + mm) * 64 + ((q4 ^ xm)) * 8;
        boff1[nb] = (nb * 16 + mm) * 64 + (((4 + q4) ^ xm)) * 8;
    }

    for (int k0 = 0; k0 < K; k0 += 64) {
        __syncthreads();
        gload16(Ag + k0, &As[ar][(tid & 7) * 8]);
        gload16(Ag2 + k0, &As[ar + 32][(tid & 7) * 8]);
        gload16(Bg + k0, &Bs[ar][(tid & 7) * 8]);
        gload16(Bg2 + k0, &Bs[ar + 32][(tid & 7) * 8]);
        __syncthreads();   // drains vmcnt (compiler emits it before s_barrier)
        short8 af0 = *(const short8*)(Asf + aoff0);
        short8 af1 = *(const short8*)(Asf + aoff1);
#pragma unroll
        for (int nb = 0; nb < 4; ++nb) {
            short8 b0 = *(const short8*)(Bsf + boff0[nb]);
            short8 b1 = *(const short8*)(Bsf + boff1[nb]);
            acc[nb] = __builtin_amdgcn_mfma_f32_16x16x32_bf16(af0, b0, acc[nb], 0, 0, 0);
            acc[nb] = __builtin_amdgcn_mfma_f32_16x16x32_bf16(af1, b1, acc[nb], 0, 0, 0);
        }
    }

    // bias add (all modes)
    float vv[4][4];   // [nb][r]
#pragma unroll
    for (int nb = 0; nb < 4; ++nb)
#pragma unroll
        for (int r = 0; r < 4; ++r)
            vv[nb][r] = acc[nb][r] + bias[n0 + nb * 16 + mm];

    if (MODE == 0) {
#pragma unroll
        for (int nb = 0; nb < 4; ++nb)
#pragma unroll
            for (int r = 0; r < 4; ++r)
                C[(size_t)(m0 + w * 16 + q4 * 4 + r) * N + n0 + nb * 16 + mm] = vv[nb][r];
    } else if (MODE == 1 || (MODE == 2 && n0 < 256)) {
        // per-row RMS norm over the 64-col head tile
#pragma unroll
        for (int r = 0; r < 4; ++r) {
            float ss = 0.f;
#pragma unroll
            for (int nb = 0; nb < 4; ++nb) ss += vv[nb][r] * vv[nb][r];
#pragma unroll
            for (int j = 8; j >= 1; j >>= 1) ss += __shfl_xor(ss, j, 64);
            float rs = 1.0f / sqrtf(ss * (1.0f / 64.0f) + 1e-8f);
            int row = m0 + w * 16 + q4 * 4 + r;
            if (MODE == 1) {
#pragma unroll
                for (int nb = 0; nb < 4; ++nb) {
                    int d = nb * 16 + mm;
                    fh[(size_t)row * DMODEL + n0 + d] =
                        (_Float16)(vv[nb][r] * rs * wn[d] * 0.125f);
                }
            } else {
                int kvh = n0 >> 6;
#pragma unroll
                for (int nb = 0; nb < 4; ++nb) {
                    int d = nb * 16 + mm;
                    fh[((size_t)kvh * TSEQ + row) * HDIM + d] =
                        (_Float16)(vv[nb][r] * rs * wn[d]);
                }
            }
        }
    } else {   // MODE 2, v block
        int kvh = (n0 - 256) >> 6;
#pragma unroll
        for (int r = 0; r < 4; ++r) {
            int row = m0 + w * 16 + q4 * 4 + r;
#pragma unroll
            for (int nb = 0; nb < 4; ++nb)
                vout[((size_t)kvh * TSEQ + row) * HDIM + nb * 16 + mm] = vv[nb][r];
        }
    }
}

// ---- fused MFMA scores + exact top-64 + softmax + V gather ----
// ZERO-BARRIER variant: 4 waves per block, wave w owns rows t0+4w..t0+4w+3.
// Each wave produces ALL 64 keys of a chunk for the 16-row A-tile (8 MFMA;
// 4x redundant production vs R10 but MfmaUtil was 0.6%), extracts its 4 rows
// (lanes q4==w hold rows 4w..4w+3 in regs 0..3), round-trips through a
// WAVE-PRIVATE LDS strip (same-wave DS ops are in-order; compiler inserts
// lgkmcnt), and merges at its own pace. NO __syncthreads in the main loop ->
// one wave's sort latency overlaps other waves' work. Per-wave static window
// (R8-validated bound) + per-row runtime gate (R7-validated). Selection /
// sort / softmax / gather code byte-identical per row to R10.
__global__ __launch_bounds__(256, 4) void attn_kernel(
    const _Float16* __restrict__ qh, const _Float16* __restrict__ kh,
    const float* __restrict__ vbuf, bf16* __restrict__ ybuf,
    const float* __restrict__ kn_w)
{
    __shared__ float Sw[4][4][68];       // wave-private score strips [w][rr][key]
    __shared__ float cbS[16][128];       // per-row candidate scores
    __shared__ int   cbI[16][128];       // per-row candidate indices
    const int tid = threadIdx.x;
    const int w = tid >> 6, lane = tid & 63;
    const int mm = lane & 15, q4 = lane >> 4;
    const int h = 15 - (blockIdx.x >> 7);            // heavy (low-slope) heads first
    const int t0 = (127 - (blockIdx.x & 127)) << 4;  // long rows first within head
    const int kvh = h >> 2;
    const float slope = exp2f(-((float)h) * (8.0f / 15.0f));
    const _Float16* kbase = kh + (size_t)kvh * TSEQ * HDIM;
    const int nch = (t0 + 15) >> 6;

    // max |kn_w| (wave-uniform)
    float kw = fabsf(kn_w[lane]);
#pragma unroll
    for (int j = 32; j > 0; j >>= 1) kw = fmaxf(kw, __shfl_xor(kw, j, 64));
    const float kfac = 8.0f * kw * 1.001f;

    // per-row exact bound B and per-WAVE window (tighter than block-wide)
    float Brow[4];
    int em = 0x7fffffff;
#pragma unroll
    for (int rr = 0; rr < 4; ++rr) {
        const int r = 4 * w + rr;
        float qe = (float)qh[(size_t)(t0 + r) * DMODEL + h * HDIM + lane];
        float qs = qe * qe;
#pragma unroll
        for (int j = 32; j > 0; j >>= 1) qs += __shfl_xor(qs, j, 64);
        Brow[rr] = sqrtf(qs) * kfac + 1e-3f;
        float Dw = 2.0f * Brow[rr] / slope + 64.0f;
        int e = (int)floorf((float)(t0 + r) - Dw);
        em = min(em, e);
    }
    const int c_min = (em > 0) ? (em >> 6) : 0;

    // Q fragments (f16, 1/8 scale folded). A-frag: row=lane&15, k=(lane>>4)*8..+7
    const _Float16* qp = qh + (size_t)(t0 + mm) * DMODEL + h * HDIM + q4 * 8;
    half8 qf0 = *(const half8*)(qp);        // d 0..31
    half8 qf1 = *(const half8*)(qp + 32);   // d 32..63

    // K regs for current chunk: kb[2*jt+half], 8 x half8
    half8 kb[8], nb[8];
#pragma unroll
    for (int jt = 0; jt < 4; ++jt) {
        const _Float16* kp = kbase + ((size_t)((nch << 6) + jt * 16 + mm)) * HDIM + q4 * 8;
        kb[2 * jt]     = *(const half8*)(kp);
        kb[2 * jt + 1] = *(const half8*)(kp + 32);
    }

    float cs[4]; int ci[4]; float thr[4]; int cnt[4];
#pragma unroll
    for (int rr = 0; rr < 4; ++rr) { cs[rr] = -1e30f; ci[rr] = 0; thr[rr] = -1e30f; cnt[rr] = 0; }

    for (int c = nch; c >= c_min; --c) {
        // issue next chunk's K loads early (hide L2 latency under merge)
        const int cn = c - 1;
        if (cn >= c_min) {
#pragma unroll
            for (int jt = 0; jt < 4; ++jt) {
                const _Float16* kp = kbase + ((size_t)((cn << 6) + jt * 16 + mm)) * HDIM + q4 * 8;
                nb[2 * jt]     = *(const half8*)(kp);
                nb[2 * jt + 1] = *(const half8*)(kp + 32);
            }
        }
        // produce all 64 keys of chunk c; keep only my 4 rows (q4 == w lanes)
#pragma unroll
        for (int jt = 0; jt < 4; ++jt) {
            f32x4 a = __builtin_amdgcn_mfma_f32_16x16x32_f16(
                qf0, kb[2 * jt], (f32x4){0.f, 0.f, 0.f, 0.f}, 0, 0, 0);
            a = __builtin_amdgcn_mfma_f32_16x16x32_f16(qf1, kb[2 * jt + 1], a, 0, 0, 0);
            // C layout: col=lane&15 (key), row=(lane>>4)*4+reg; rows 4w+rr <=> q4==w
            if (q4 == w) {
#pragma unroll
                for (int rr = 0; rr < 4; ++rr)
                    Sw[w][rr][jt * 16 + mm] = a[rr];
            }
        }
        // merge chunk c for my 4 rows (same-wave LDS: lgkmcnt auto-inserted)
        const int jb = c << 6;
#pragma unroll
        for (int rr = 0; rr < 4; ++rr) {
            const int r = 4 * w + rr;
            // per-row runtime prune (validated): chunk can't reach th
            int dm = (t0 + r - 63) - jb;
            float dmin = (float)(dm > 0 ? dm : 0);
            if (Brow[rr] - slope * dmin < thr[rr]) continue;
            float sr = Sw[w][rr][lane];
            int dist = (t0 + r) - (jb + lane);
            float s = sr - slope * (float)dist;
            bool pass = (dist >= 0) && (s >= thr[rr]);
            unsigned long long mk = __ballot(pass);
            if (mk) {
                int rank = __popcll(mk & ((1ull << lane) - 1ull));
                if (pass) { cbS[r][cnt[rr] + rank] = s; cbI[r][cnt[rr] + rank] = jb + lane; }
                cnt[rr] += __popcll(mk);
                if (cnt[rr] >= 64) {
                    float ns = cbS[r][lane];
                    int   ni = cbI[r][lane];
                    bsort(ns, ni, lane);
                    float rsv = __shfl_xor(ns, 63, 64);   // descending view
                    int   riv = __shfl_xor(ni, 63, 64);
                    if (pgt(rsv, riv, cs[rr], ci[rr])) { cs[rr] = rsv; ci[rr] = riv; }
                    bmerge(cs[rr], ci[rr], lane);          // restore ascending
                    thr[rr] = __shfl(cs[rr], 0, 64);
                    int rem = cnt[rr] - 64;
                    float ms = 0.f; int mi = 0;
                    if (lane < rem) { ms = cbS[r][64 + lane]; mi = cbI[r][64 + lane]; }
                    if (lane < rem) { cbS[r][lane] = ms; cbI[r][lane] = mi; }
                    cnt[rr] = rem;
                }
            }
        }
        // rotate prefetched K into place
        if (cn >= c_min) {
#pragma unroll
            for (int i2 = 0; i2 < 8; ++i2) kb[i2] = nb[i2];
        }
    }

    // epilogue per row: flush, softmax, V gather, store
    const float* vb = vbuf + (size_t)kvh * TSEQ * HDIM + lane;
#pragma unroll
    for (int rr = 0; rr < 4; ++rr) {
        const int r = 4 * w + rr;
        if (cnt[rr] > 0) {
            float ns = (lane < cnt[rr]) ? cbS[r][lane] : -2e30f;
            int   ni = (lane < cnt[rr]) ? cbI[r][lane] : 0;
            bsort(ns, ni, lane);
            float rsv = __shfl_xor(ns, 63, 64);
            int   riv = __shfl_xor(ni, 63, 64);
            if (pgt(rsv, riv, cs[rr], ci[rr])) { cs[rr] = rsv; ci[rr] = riv; }
            bmerge(cs[rr], ci[rr], lane);
        }
        // softmax over kept 64 (pads -1e30 -> weight 0); max at lane 63
        float msx = __shfl(cs[rr], 63, 64);
        bool valid = cs[rr] > -1e29f;
        float pr = valid ? __expf(cs[rr] - msx) : 0.f;
        float l = pr;
#pragma unroll
        for (int j2 = 32; j2 > 0; j2 >>= 1) l += __shfl_xor(l, j2, 64);
        float wgt = pr / l;
        int widx = valid ? ci[rr] : 0;
        float acc = 0.f;
#pragma unroll 8
        for (int i = 0; i < 64; ++i) {
            float wv = __shfl(wgt, i, 64);
            int  ix = __shfl(widx, i, 64);
            acc += wv * vb[(size_t)ix * HDIM];
        }
        ybuf[(size_t)(t0 + r) * DMODEL + h * HDIM + lane] = __float2bfloat16(acc);
    }
}

extern "C" void kernel_launch(void* const* d_in, const int* in_sizes, int n_in,
                              void* d_out, int out_size, void* d_ws, size_t ws_size,
                              hipStream_t stream)
{
    // d_in order: x, wq, bq, wkv, bkv, wo, bo, qn_w, kn_w  (all fp32)
    const float* x    = (const float*)d_in[0];
    const float* wq   = (const float*)d_in[1];
    const float* bq   = (const float*)d_in[2];
    const float* wkv  = (const float*)d_in[3];
    const float* bkv  = (const float*)d_in[4];
    const float* wo   = (const float*)d_in[5];
    const float* bo   = (const float*)d_in[6];
    const float* qn_w = (const float*)d_in[7];
    const float* kn_w = (const float*)d_in[8];
    char* ws = (char*)d_ws;
    // ws layout (28 MB):
    // cx bf16 4M @0 | cwqT 2M @4M | cwkvT 1M @6M | cwoT 2M @7M |
    // qh f16 4M @9M | kh f16 1M @21M | vbuf fp32 2M @22M |
    // ybuf bf16 4M @24M..28M  (no overlaps; norm fused into GEMM epilogues)
    bf16*      cx    = (bf16*)(ws);
    bf16*      cwqT  = (bf16*)(ws + ((size_t)4  << 20));   // [1024][1024] (n,k)
    bf16*      cwkvT = (bf16*)(ws + ((size_t)6  << 20));   // [512][1024]  (n,k)
    bf16*      cwoT  = (bf16*)(ws + ((size_t)7  << 20));   // [1024][1024] (n,k)
    _Float16*  qh    = (_Float16*)(ws + ((size_t)9  << 20));
    _Float16*  kh    = (_Float16*)(ws + ((size_t)21 << 20));
    float*     vbuf  = (float*)(ws + ((size_t)22 << 20));
    bf16*      ybuf  = (bf16*)(ws + ((size_t)24 << 20));
    float*     out   = (float*)d_out;   // fp32 output

    convert_x<<<1024, 256, 0, stream>>>(x, cx);
    transpose_conv<<<dim3(32, 32), 256, 0, stream>>>(wq, cwqT, 1024, 1024);
    transpose_conv<<<dim3(16, 32), 256, 0, stream>>>(wkv, cwkvT, 1024, 512);
    transpose_conv<<<dim3(32, 32), 256, 0, stream>>>(wo, cwoT, 1024, 1024);
    gemm_bias<1><<<dim3(DMODEL / 64, TSEQ / 64), 256, 0, stream>>>(
        cx, cwqT, bq, nullptr, qh, nullptr, qn_w, TSEQ, DMODEL, DMODEL);
    gemm_bias<2><<<dim3(512 / 64, TSEQ / 64), 256, 0, stream>>>(
        cx, cwkvT, bkv, nullptr, kh, vbuf, kn_w, TSEQ, 512, DMODEL);
    attn_kernel<<<NH * (TSEQ / 16), 256, 0, stream>>>(qh, kh, vbuf, ybuf, kn_w);
    gemm_bias<0><<<dim3(DMODEL / 64, TSEQ / 64), 256, 0, stream>>>(
        ybuf, cwoT, bo, out, nullptr, nullptr, nullptr, TSEQ, DMODEL, DMODEL);
}

// Round 12
// 248.089 us; speedup vs baseline: 1.1615x; 1.1615x over previous
//
#include <hip/hip_runtime.h>
#include <hip/hip_bf16.h>
#include <stdint.h>

// Problem constants (fixed by reference)
#define TSEQ   2048
#define DMODEL 1024
#define NH     16
#define HDIM   64
#define NKVH   4
#define NITEMS (NH * (TSEQ / 16))

typedef __attribute__((ext_vector_type(8))) short short8;
typedef __attribute__((ext_vector_type(8))) _Float16 half8;
typedef __attribute__((ext_vector_type(4))) float f32x4;
typedef __hip_bfloat16 bf16;

// async global->LDS, 16B per lane (linear LDS dest = wave base + lane*16)
__device__ __forceinline__ void gload16(const void* g, void* l) {
    __builtin_amdgcn_global_load_lds(
        (const __attribute__((address_space(1))) uint32_t*)g,
        (__attribute__((address_space(3))) uint32_t*)l, 16, 0, 0);
}

// priority comparator: higher score wins; tie -> lower index wins (matches jax top_k)
__device__ __forceinline__ bool pgt(float as, int ai, float bs, int bi) {
    return (as > bs) || (as == bs && ai < bi);
}

// full bitonic sort across 64 lanes, ascending by priority (validated R6)
__device__ __forceinline__ void bsort(float& s, int& i, int lane) {
#pragma unroll
    for (int k = 2; k <= 64; k <<= 1) {
#pragma unroll
        for (int j = k >> 1; j > 0; j >>= 1) {
            float os = __shfl_xor(s, j, 64);
            int   oi = __shfl_xor(i, j, 64);
            bool lower = (lane & j) == 0;
            bool asc   = (lane & k) == 0;
            bool wmin  = (lower == asc);
            bool takeo = (pgt(s, i, os, oi) == wmin);
            if (takeo) { s = os; i = oi; }
        }
    }
}

// bitonic -> ascending cleanup (6 stages) (validated R6)
__device__ __forceinline__ void bmerge(float& s, int& i, int lane) {
#pragma unroll
    for (int j = 32; j > 0; j >>= 1) {
        float os = __shfl_xor(s, j, 64);
        int   oi = __shfl_xor(i, j, 64);
        bool lower = (lane & j) == 0;
        bool takeo = (pgt(s, i, os, oi) == lower);
        if (takeo) { s = os; i = oi; }
    }
}

// ---- fused prep: zero work counter, fp32->bf16 convert x, transpose-convert
//      the three weights. Block-range dispatch (4 launches -> 1).
__global__ __launch_bounds__(256) void prep_kernel(
    const float* __restrict__ x, const float* __restrict__ wq,
    const float* __restrict__ wkv, const float* __restrict__ wo,
    bf16* __restrict__ cx, bf16* __restrict__ cwqT,
    bf16* __restrict__ cwkvT, bf16* __restrict__ cwoT, int* __restrict__ gcnt)
{
    __shared__ float tile[32][33];
    const int bid = blockIdx.x;
    if (bid == 0 && threadIdx.x == 0) *gcnt = 0;
    if (bid < 1024) {
        const size_t i0 = (size_t)bid * 256 + threadIdx.x;
        for (size_t i = i0; i < 2097152; i += 262144) cx[i] = __float2bfloat16(x[i]);
        return;
    }
    const float* in; bf16* out; int R, Cc, bx, by;
    if (bid < 2048) {        // wq: 1024x1024, 32x32 col-tiles
        int idx = bid - 1024; in = wq; out = cwqT; R = 1024; Cc = 1024;
        bx = (idx & 31) << 5; by = (idx >> 5) << 5;
    } else if (bid < 2560) { // wkv: 1024x512, 16 col-tiles x 32 row-tiles
        int idx = bid - 2048; in = wkv; out = cwkvT; R = 1024; Cc = 512;
        bx = (idx & 15) << 5; by = (idx >> 4) << 5;
    } else {                 // wo: 1024x1024
        int idx = bid - 2560; in = wo; out = cwoT; R = 1024; Cc = 1024;
        bx = (idx & 31) << 5; by = (idx >> 5) << 5;
    }
    const int tx = threadIdx.x & 31, ty = threadIdx.x >> 5;   // 32 x 8
#pragma unroll
    for (int i = 0; i < 32; i += 8)
        tile[ty + i][tx] = in[(size_t)(by + ty + i) * Cc + bx + tx];
    __syncthreads();
#pragma unroll
    for (int i = 0; i < 32; i += 8)
        out[(size_t)(bx + ty + i) * R + by + tx] = __float2bfloat16(tile[tx][ty + i]);
}

// ---- fused Q+KV GEMM: one launch; bx<16 = Q (RMSnorm*0.125 -> qh),
//      bx>=16 = KV (k: RMSnorm -> kh; v: fp32 -> vbuf). Core loop = validated R4.
__global__ __launch_bounds__(256) void gemm_qkv(
    const bf16* __restrict__ A, const bf16* __restrict__ BTq,
    const bf16* __restrict__ BTkv, const float* __restrict__ bq,
    const float* __restrict__ bkv, _Float16* __restrict__ qh,
    _Float16* __restrict__ kh, float* __restrict__ vbuf,
    const float* __restrict__ qn_w, const float* __restrict__ kn_w)
{
    __shared__ short As[64][64];
    __shared__ short Bs[64][64];
    const int tid = threadIdx.x;
    const int bx = blockIdx.x;
    const bool isQ = bx < 16;
    const bf16* BT = isQ ? BTq : BTkv;
    const float* bias = isQ ? bq : bkv;
    const float* wn = isQ ? qn_w : kn_w;
    const int n0 = (isQ ? bx : bx - 16) * 64;
    const int K = 1024;
    const int m0 = blockIdx.y * 64;
    const int w = tid >> 6, lane = tid & 63;
    const int q4 = lane >> 4, mm = lane & 15;
    f32x4 acc[4];
#pragma unroll
    for (int nb = 0; nb < 4; ++nb) acc[nb] = (f32x4){0.f, 0.f, 0.f, 0.f};

    const int ar = tid >> 3;
    const int sslot = (tid & 7) ^ (ar & 7);
    const short* Ag = (const short*)A + (size_t)(m0 + ar) * K + sslot * 8;
    const short* Ag2 = (const short*)A + (size_t)(m0 + ar + 32) * K + ((tid & 7) ^ ((ar + 32) & 7)) * 8;
    const short* Bg = (const short*)BT + (size_t)(n0 + ar) * K + sslot * 8;
    const short* Bg2 = (const short*)BT + (size_t)(n0 + ar + 32) * K + ((tid & 7) ^ ((ar + 32) & 7)) * 8;

    const int xm = mm & 7;
    const short* Asf = (const short*)As;
    const short* Bsf = (const short*)Bs;
    const int aoff0 = (w * 16 + mm) * 64 + ((q4 ^ xm)) * 8;
    const int aoff1 = (w * 16 + mm) * 64 + (((4 + q4) ^ xm)) * 8;
    int boff0[4], boff1[4];
#pragma unroll
    for (int nb = 0; nb < 4; ++nb) {
        boff0[nb] = (nb * 16 + mm) * 64 + ((q4 ^ xm)) * 8;
        boff1[nb] = (nb * 16 + mm) * 64 + (((4 + q4) ^ xm)) * 8;
    }

    for (int k0 = 0; k0 < K; k0 += 64) {
        __syncthreads();
        gload16(Ag + k0, &As[ar][(tid & 7) * 8]);
        gload16(Ag2 + k0, &As[ar + 32][(tid & 7) * 8]);
        gload16(Bg + k0, &Bs[ar][(tid & 7) * 8]);
        gload16(Bg2 + k0, &Bs[ar + 32][(tid & 7) * 8]);
        __syncthreads();
        short8 af0 = *(const short8*)(Asf + aoff0);
        short8 af1 = *(const short8*)(Asf + aoff1);
#pragma unroll
        for (int nb = 0; nb < 4; ++nb) {
            short8 b0 = *(const short8*)(Bsf + boff0[nb]);
            short8 b1 = *(const short8*)(Bsf + boff1[nb]);
            acc[nb] = __builtin_amdgcn_mfma_f32_16x16x32_bf16(af0, b0, acc[nb], 0, 0, 0);
            acc[nb] = __builtin_amdgcn_mfma_f32_16x16x32_bf16(af1, b1, acc[nb], 0, 0, 0);
        }
    }

    float vv[4][4];
#pragma unroll
    for (int nb = 0; nb < 4; ++nb)
#pragma unroll
        for (int r = 0; r < 4; ++r)
            vv[nb][r] = acc[nb][r] + bias[n0 + nb * 16 + mm];

    if (isQ || n0 < 256) {
        // per-row RMS norm over the 64-col head tile
#pragma unroll
        for (int r = 0; r < 4; ++r) {
            float ss = 0.f;
#pragma unroll
            for (int nb = 0; nb < 4; ++nb) ss += vv[nb][r] * vv[nb][r];
#pragma unroll
            for (int j = 8; j >= 1; j >>= 1) ss += __shfl_xor(ss, j, 64);
            float rs = 1.0f / sqrtf(ss * (1.0f / 64.0f) + 1e-8f);
            int row = m0 + w * 16 + q4 * 4 + r;
            if (isQ) {
#pragma unroll
                for (int nb = 0; nb < 4; ++nb) {
                    int d = nb * 16 + mm;
                    qh[(size_t)row * DMODEL + n0 + d] =
                        (_Float16)(vv[nb][r] * rs * wn[d] * 0.125f);
                }
            } else {
                int kvh = n0 >> 6;
#pragma unroll
                for (int nb = 0; nb < 4; ++nb) {
                    int d = nb * 16 + mm;
                    kh[((size_t)kvh * TSEQ + row) * HDIM + d] =
                        (_Float16)(vv[nb][r] * rs * wn[d]);
                }
            }
        }
    } else {   // v block
        int kvh = (n0 - 256) >> 6;
#pragma unroll
        for (int r = 0; r < 4; ++r) {
            int row = m0 + w * 16 + q4 * 4 + r;
#pragma unroll
            for (int nb = 0; nb < 4; ++nb)
                vbuf[((size_t)kvh * TSEQ + row) * HDIM + nb * 16 + mm] = vv[nb][r];
        }
    }
}

// ---- out projection GEMM (validated R4 core, MODE 0 epilogue) ----
__global__ __launch_bounds__(256) void gemm_out(
    const bf16* __restrict__ A, const bf16* __restrict__ BT,
    const float* __restrict__ bias, float* __restrict__ C, int M, int N, int K)
{
    __shared__ short As[64][64];
    __shared__ short Bs[64][64];
    const int tid = threadIdx.x;
    const int m0 = blockIdx.y * 64, n0 = blockIdx.x * 64;
    const int w = tid >> 6, lane = tid & 63;
    const int q4 = lane >> 4, mm = lane & 15;
    f32x4 acc[4];
#pragma unroll
    for (int nb = 0; nb < 4; ++nb) acc[nb] = (f32x4){0.f, 0.f, 0.f, 0.f};

    const int ar = tid >> 3;
    const int sslot = (tid & 7) ^ (ar & 7);
    const short* Ag = (const short*)A + (size_t)(m0 + ar) * K + sslot * 8;
    const short* Ag2 = (const short*)A + (size_t)(m0 + ar + 32) * K + ((tid & 7) ^ ((ar + 32) & 7)) * 8;
    const short* Bg = (const short*)BT + (size_t)(n0 + ar) * K + sslot * 8;
    const short* Bg2 = (const short*)BT + (size_t)(n0 + ar + 32) * K + ((tid & 7) ^ ((ar + 32) & 7)) * 8;

    const int xm = mm & 7;
    const short* Asf = (const short*)As;
    const short* Bsf = (const short*)Bs;
    const int aoff0 = (w * 16 + mm) * 64 + ((q4 ^ xm)) * 8;
    const int aoff1 = (w * 16 + mm) * 64 + (((4 + q4) ^ xm)) * 8;
    int boff0[4], boff1[4];
#pragma unroll
    for (int nb = 0; nb < 4; ++nb) {
        boff0[nb] = (nb * 16 + mm) * 64 + ((q4 ^ xm)) * 8;
        boff1[nb] = (nb * 16 + mm) * 64 + (((4 + q4) ^ xm)) * 8;
    }

    for (int k0 = 0; k0 < K; k0 += 64) {
        __syncthreads();
        gload16(Ag + k0, &As[ar][(tid & 7) * 8]);
        gload16(Ag2 + k0, &As[ar + 32][(tid & 7) * 8]);
        gload16(Bg + k0, &Bs[ar][(tid & 7) * 8]);
        gload16(Bg2 + k0, &Bs[ar + 32][(tid & 7) * 8]);
        __syncthreads();
        short8 af0 = *(const short8*)(Asf + aoff0);
        short8 af1 = *(const short8*)(Asf + aoff1);
#pragma unroll
        for (int nb = 0; nb < 4; ++nb) {
            short8 b0 = *(const short8*)(Bsf + boff0[nb]);
            short8 b1 = *(const short8*)(Bsf + boff1[nb]);
            acc[nb] = __builtin_amdgcn_mfma_f32_16x16x32_bf16(af0, b0, acc[nb], 0, 0, 0);
            acc[nb] = __builtin_amdgcn_mfma_f32_16x16x32_bf16(af1, b1, acc[nb], 0, 0, 0);
        }
    }
#pragma unroll
    for (int nb = 0; nb < 4; ++nb)
#pragma unroll
        for (int r = 0; r < 4; ++r)
            C[(size_t)(m0 + w * 16 + q4 * 4 + r) * N + n0 + nb * 16 + mm]
                = acc[nb][r] + bias[n0 + nb * 16 + mm];
}

// ---- fused MFMA scores + exact top-64 + softmax + V gather ----
// PERSISTENT-BLOCK version of the validated R10 kernel: 1536 blocks (6/CU)
// dynamically claim (h, 16-row) items heavy-first via atomicAdd -> evens the
// tail that capped R10 at 40% occupancy. Per-item body byte-identical to R10
// (cooperative chunk production, candidate buffer, static window + runtime
// gate, bitonic top-64). Output independent of block->item assignment.
__global__ __launch_bounds__(256, 4) void attn_kernel(
    const _Float16* __restrict__ qh, const _Float16* __restrict__ kh,
    const float* __restrict__ vbuf, bf16* __restrict__ ybuf,
    const float* __restrict__ kn_w, int* __restrict__ gcnt)
{
    __shared__ float Sg[2][16][68];      // [buf][qrow][key] one chunk
    __shared__ float cbS[16][128];       // per-row candidate scores
    __shared__ int   cbI[16][128];       // per-row candidate indices
    __shared__ int   eminS[4];           // per-wave earliest needed key
    __shared__ int   witem;              // claimed work item
    const int tid = threadIdx.x;
    const int w = tid >> 6, lane = tid & 63;
    const int mm = lane & 15, q4 = lane >> 4;

    // max |kn_w| (item-independent, hoisted)
    float kw = fabsf(kn_w[lane]);
#pragma unroll
    for (int j = 32; j > 0; j >>= 1) kw = fmaxf(kw, __shfl_xor(kw, j, 64));
    const float kfac = 8.0f * kw * 1.001f;

    while (true) {
        if (tid == 0) witem = atomicAdd(gcnt, 1);
        __syncthreads();                 // publish witem; orders vs prior item
        const int item = witem;
        if (item >= NITEMS) break;       // block-uniform
        const int h = 15 - (item >> 7);            // heavy (low-slope) heads first
        const int t0 = (127 - (item & 127)) << 4;  // long rows first within head
        const int kvh = h >> 2;
        const float slope = exp2f(-((float)h) * (8.0f / 15.0f));
        const _Float16* kbase = kh + (size_t)kvh * TSEQ * HDIM;
        const int nch = (t0 + 15) >> 6;

        // per-row exact bound B and window for this wave's rows r = 4w+rr
        float Brow[4];
        int em = 0x7fffffff;
#pragma unroll
        for (int rr = 0; rr < 4; ++rr) {
            const int r = 4 * w + rr;
            float qe = (float)qh[(size_t)(t0 + r) * DMODEL + h * HDIM + lane];
            float qs = qe * qe;
#pragma unroll
            for (int j = 32; j > 0; j >>= 1) qs += __shfl_xor(qs, j, 64);
            Brow[rr] = sqrtf(qs) * kfac + 1e-3f;
            float Dw = 2.0f * Brow[rr] / slope + 64.0f;
            int e = (int)floorf((float)(t0 + r) - Dw);
            em = min(em, e);
        }
        if (lane == 0) eminS[w] = em;

        // Q fragments (f16, 1/8 scale folded). A-frag: row=lane&15, k=q4*8..+7
        const _Float16* qp = qh + (size_t)(t0 + mm) * DMODEL + h * HDIM + q4 * 8;
        half8 qf0 = *(const half8*)(qp);        // d 0..31
        half8 qf1 = *(const half8*)(qp + 32);   // d 32..63

        // prologue: produce chunk nch into buffer 0 (wave w -> keys w*16..+15)
        {
            const int jb = nch << 6;
            const _Float16* kp = kbase + ((size_t)(jb + w * 16 + mm)) * HDIM + q4 * 8;
            half8 b0 = *(const half8*)(kp);
            half8 b1 = *(const half8*)(kp + 32);
            f32x4 a = __builtin_amdgcn_mfma_f32_16x16x32_f16(
                qf0, b0, (f32x4){0.f, 0.f, 0.f, 0.f}, 0, 0, 0);
            a = __builtin_amdgcn_mfma_f32_16x16x32_f16(qf1, b1, a, 0, 0, 0);
#pragma unroll
            for (int rr = 0; rr < 4; ++rr)
                Sg[0][q4 * 4 + rr][w * 16 + mm] = a[rr];
        }
        __syncthreads();

        // block-uniform earliest chunk (conservative: min over all rows)
        int em4 = min(min(eminS[0], eminS[1]), min(eminS[2], eminS[3]));
        const int c_min = (em4 > 0) ? (em4 >> 6) : 0;

        float cs[4]; int ci[4]; float thr[4]; int cnt[4];
#pragma unroll
        for (int rr = 0; rr < 4; ++rr) { cs[rr] = -1e30f; ci[rr] = 0; thr[rr] = -1e30f; cnt[rr] = 0; }

        int p = 0;
        for (int c = nch; c >= c_min; --c) {
            // issue next chunk's K loads early (hide L2 latency under merge)
            const int cn = c - 1;
            half8 b0, b1;
            if (cn >= c_min) {
                const _Float16* kp = kbase + ((size_t)((cn << 6) + w * 16 + mm)) * HDIM + q4 * 8;
                b0 = *(const half8*)(kp);
                b1 = *(const half8*)(kp + 32);
            }
            // merge chunk c for this wave's 4 rows
            const int jb = c << 6;
#pragma unroll
            for (int rr = 0; rr < 4; ++rr) {
                const int r = 4 * w + rr;
                int dm = (t0 + r - 63) - jb;
                float dmin = (float)(dm > 0 ? dm : 0);
                if (Brow[rr] - slope * dmin < thr[rr]) continue;
                float sr = Sg[p][r][lane];
                int dist = (t0 + r) - (jb + lane);
                float s = sr - slope * (float)dist;
                bool pass = (dist >= 0) && (s >= thr[rr]);
                unsigned long long mk = __ballot(pass);
                if (mk) {
                    int rank = __popcll(mk & ((1ull << lane) - 1ull));
                    if (pass) { cbS[r][cnt[rr] + rank] = s; cbI[r][cnt[rr] + rank] = jb + lane; }
                    cnt[rr] += __popcll(mk);
                    if (cnt[rr] >= 64) {
                        float ns = cbS[r][lane];
                        int   ni = cbI[r][lane];
                        bsort(ns, ni, lane);
                        float rsv = __shfl_xor(ns, 63, 64);   // descending view
                        int   riv = __shfl_xor(ni, 63, 64);
                        if (pgt(rsv, riv, cs[rr], ci[rr])) { cs[rr] = rsv; ci[rr] = riv; }
                        bmerge(cs[rr], ci[rr], lane);          // restore ascending
                        thr[rr] = __shfl(cs[rr], 0, 64);
                        int rem = cnt[rr] - 64;
                        float ms = 0.f; int mi = 0;
                        if (lane < rem) { ms = cbS[r][64 + lane]; mi = cbI[r][64 + lane]; }
                        if (lane < rem) { cbS[r][lane] = ms; cbI[r][lane] = mi; }
                        cnt[rr] = rem;
                    }
                }
            }
            // produce next chunk into the other buffer
            if (cn >= c_min) {
                f32x4 a = __builtin_amdgcn_mfma_f32_16x16x32_f16(
                    qf0, b0, (f32x4){0.f, 0.f, 0.f, 0.f}, 0, 0, 0);
                a = __builtin_amdgcn_mfma_f32_16x16x32_f16(qf1, b1, a, 0, 0, 0);
#pragma unroll
                for (int rr = 0; rr < 4; ++rr)
                    Sg[p ^ 1][q4 * 4 + rr][w * 16 + mm] = a[rr];
            }
            p ^= 1;
            __syncthreads();
        }

        // epilogue per row: flush, softmax, V gather, store
        const float* vb = vbuf + (size_t)kvh * TSEQ * HDIM + lane;
#pragma unroll
        for (int rr = 0; rr < 4; ++rr) {
            const int r = 4 * w + rr;
            if (cnt[rr] > 0) {
                float ns = (lane < cnt[rr]) ? cbS[r][lane] : -2e30f;
                int   ni = (lane < cnt[rr]) ? cbI[r][lane] : 0;
                bsort(ns, ni, lane);
                float rsv = __shfl_xor(ns, 63, 64);
                int   riv = __shfl_xor(ni, 63, 64);
                if (pgt(rsv, riv, cs[rr], ci[rr])) { cs[rr] = rsv; ci[rr] = riv; }
                bmerge(cs[rr], ci[rr], lane);
            }
            // softmax over kept 64 (pads -1e30 -> weight 0); max at lane 63
            float msx = __shfl(cs[rr], 63, 64);
            bool valid = cs[rr] > -1e29f;
            float pr = valid ? __expf(cs[rr] - msx) : 0.f;
            float l = pr;
#pragma unroll
            for (int j2 = 32; j2 > 0; j2 >>= 1) l += __shfl_xor(l, j2, 64);
            float wgt = pr / l;
            int widx = valid ? ci[rr] : 0;
            float acc = 0.f;
#pragma unroll 8
            for (int i = 0; i < 64; ++i) {
                float wv = __shfl(wgt, i, 64);
                int  ix = __shfl(widx, i, 64);
                acc += wv * vb[(size_t)ix * HDIM];
            }
            ybuf[(size_t)(t0 + r) * DMODEL + h * HDIM + lane] = __float2bfloat16(acc);
        }
    }
}

extern "C" void kernel_launch(void* const* d_in, const int* in_sizes, int n_in,
                              void* d_out, int out_size, void* d_ws, size_t ws_size,
                              hipStream_t stream)
{
    // d_in order: x, wq, bq, wkv, bkv, wo, bo, qn_w, kn_w  (all fp32)
    const float* x    = (const float*)d_in[0];
    const float* wq   = (const float*)d_in[1];
    const float* bq   = (const float*)d_in[2];
    const float* wkv  = (const float*)d_in[3];
    const float* bkv  = (const float*)d_in[4];
    const float* wo   = (const float*)d_in[5];
    const float* bo   = (const float*)d_in[6];
    const float* qn_w = (const float*)d_in[7];
    const float* kn_w = (const float*)d_in[8];
    char* ws = (char*)d_ws;
    // ws layout (28 MB):
    // cx bf16 4M @0 | cwqT 2M @4M | cwkvT 1M @6M | cwoT 2M @7M |
    // qh f16 4M @9M | gcnt @13M | kh f16 1M @21M | vbuf fp32 2M @22M |
    // ybuf bf16 4M @24M..28M  (no overlaps)
    bf16*      cx    = (bf16*)(ws);
    bf16*      cwqT  = (bf16*)(ws + ((size_t)4  << 20));   // [1024][1024] (n,k)
    bf16*      cwkvT = (bf16*)(ws + ((size_t)6  << 20));   // [512][1024]  (n,k)
    bf16*      cwoT  = (bf16*)(ws + ((size_t)7  << 20));   // [1024][1024] (n,k)
    _Float16*  qh    = (_Float16*)(ws + ((size_t)9  << 20));
    int*       gcnt  = (int*)(ws + ((size_t)13 << 20));
    _Float16*  kh    = (_Float16*)(ws + ((size_t)21 << 20));
    float*     vbuf  = (float*)(ws + ((size_t)22 << 20));
    bf16*      ybuf  = (bf16*)(ws + ((size_t)24 << 20));
    float*     out   = (float*)d_out;   // fp32 output

    prep_kernel<<<3584, 256, 0, stream>>>(x, wq, wkv, wo, cx, cwqT, cwkvT, cwoT, gcnt);
    gemm_qkv<<<dim3(24, TSEQ / 64), 256, 0, stream>>>(
        cx, cwqT, cwkvT, bq, bkv, qh, kh, vbuf, qn_w, kn_w);
    attn_kernel<<<1536, 256, 0, stream>>>(qh, kh, vbuf, ybuf, kn_w, gcnt);
    gemm_out<<<dim3(DMODEL / 64, TSEQ / 64), 256, 0, stream>>>(
        ybuf, cwoT, bo, out, TSEQ, DMODEL, DMODEL);
}